// Round 5
// baseline (59.176 us; speedup 1.0000x reference)
//
#include <hip/hip_runtime.h>
#include <math.h>
#include <float.h>

// VQ-VAE quantizer, round 5: occupancy via 512-thr blocks + shared streams.
// 512 blocks x 8 waves. Block = 64 points. Wave (pg,kq): pg point-set (32 pts),
// kq codebook quarter (256 codes, 8 chunks of 32). pg0 stages the quarter's
// chunk stream (double-buffered); ONE __syncthreads per chunk (its vmcnt drain
// guarantees the prefetch issued one chunk earlier has landed).
// score(t,k) = x.eh_k - |e_k|^2/2 via 2 fp16 MFMAs (x = xh+xl exact split).
// Packed top-3 per (lane-half, quarter): score bits with low-10 mantissa
// replaced by (1023-k) -> top-k tracking is a pure fmax/fmin sort network.
// Exact fp32 rescore of 12 candidates -> argmin (verified hedge).

typedef __attribute__((ext_vector_type(8))) _Float16 f16x8;
typedef __attribute__((ext_vector_type(16))) float f32x16;

#define EH2_OFF   65536    // 4 KB: -0.5*|e|^2 all 1024 codes
#define KCND_OFF  69632    // 12*64 ints
#define D2S_OFF   72704    // 12*64 floats
#define KFIN_OFF  75776    // 64 ints
#define WSUM_OFF  76032    // 8 floats
#define SMEM_BYTES 76096

typedef __attribute__((address_space(1))) const void gas_t;
typedef __attribute__((address_space(3))) void las_t;
__device__ __forceinline__ void glds16(const void* g, void* l) {
  __builtin_amdgcn_global_load_lds((gas_t*)g, (las_t*)l, 16, 0, 0);
}

// ---- prep: emb f32 -> eh fp16 [1024][128] + eh2 = -0.5*|e|^2 (f32) ----
__global__ __launch_bounds__(256)
void vq_prep(const float* __restrict__ emb, _Float16* __restrict__ ehg,
             float* __restrict__ eh2g) {
  const int tid = threadIdx.x;
  const int r = blockIdx.x * 16 + (tid >> 4);
  const int seg = tid & 15;
  const float* row = emb + (size_t)r * 128 + seg * 8;
  float4 f0 = *(const float4*)&row[0];
  float4 f1 = *(const float4*)&row[4];
  float fv[8] = {f0.x, f0.y, f0.z, f0.w, f1.x, f1.y, f1.z, f1.w};
  f16x8 H;
  float ssq = 0.f;
#pragma unroll
  for (int j = 0; j < 8; ++j) {
    float f = fv[j];
    ssq = fmaf(f, f, ssq);
    H[j] = (_Float16)f;
  }
  *(f16x8*)(ehg + (size_t)r * 128 + seg * 8) = H;
#pragma unroll
  for (int off = 1; off < 16; off <<= 1) ssq += __shfl_xor(ssq, off, 64);
  if (seg == 0) eh2g[r] = -0.5f * ssq;
}

__global__ __launch_bounds__(512, 4)
void vq_main(const float* __restrict__ x, const float* __restrict__ emb,
             const _Float16* __restrict__ ehg, const float* __restrict__ eh2g,
             float* __restrict__ out, float* __restrict__ partial) {
  __shared__ __align__(16) char smem[SMEM_BYTES];
  float* eh2s = (float*)(smem + EH2_OFF);
  int*   kcnd = (int*)(smem + KCND_OFF);
  float* scs  = (float*)(smem + D2S_OFF);
  int*   kfin = (int*)(smem + KFIN_OFF);
  float* wsum = (float*)(smem + WSUM_OFF);

  const int tid = threadIdx.x;
  const int lane = tid & 63;
  const int w = tid >> 6;          // 0..7
  const int pg = w & 1;            // point set (32 pts)
  const int kq = w >> 1;           // codebook quarter (256 codes)
  const int hf = lane >> 5;        // K-half of mfma fragment
  const int c32 = lane & 31;       // mfma column / code row
  const int blk = blockIdx.x;
  const int b = blk >> 5;
  const int t0 = (blk & 31) << 6;
  const int pw = pg * 32 + c32;    // point within 64-pt tile
  const size_t bOff = (size_t)b * 262144;

  char* sbuf = smem + kq * 16384;  // quarter's chunk double-buffer
  const char* gq = (const char*)ehg + (size_t)kq * 65536;

  // ---- issue staging: pg0 -> chunks 0,1 of its quarter; pg1 -> eh2 quarter ----
  if (pg == 0) {
#pragma unroll
    for (int c = 0; c < 2; ++c)
#pragma unroll
      for (int i = 0; i < 8; ++i) {
        int o = c * 8192 + i * 1024 + lane * 16;
        int s = o ^ (((o >> 8) & 15) << 4);   // inverse swizzle on global src
        glds16(gq + s, sbuf + o);
      }
  } else {
    glds16((const char*)eh2g + kq * 1024 + lane * 16, smem + EH2_OFF + kq * 1024);
  }

  // ---- x B-fragments: fp32 global -> exact fp16 hi/lo pairs (1 set) ----
  f16x8 xh[8], xl[8];
  {
    const float* xp = x + bOff + t0 + pw;
    const int dbase = hf * 8;
#pragma unroll
    for (int ds = 0; ds < 8; ++ds)
#pragma unroll
      for (int j = 0; j < 8; ++j) {
        float f = xp[(size_t)(ds * 16 + dbase + j) * 2048];
        _Float16 h = (_Float16)f;
        xh[ds][j] = h;
        xl[ds][j] = (_Float16)(f - (float)h);
      }
  }

  __syncthreads();   // drains everything: x, eh2, chunks 0,1

  const float NEG = __uint_as_float(0xFF800000u);   // -inf
  float v1 = NEG, v2 = NEG, v3 = NEG;

  for (int c = 0; c < 8; ++c) {
    const char* buf = sbuf + (c & 1) * 8192;
    const int kb = kq * 256 + c * 32;
    // C-init: acc[reg] = -0.5*|e_k|^2, k = kb + (reg&3) + 8*(reg>>2) + 4*hf
    f32x16 acc;
#pragma unroll
    for (int q = 0; q < 4; ++q) {
      float4 v = *(const float4*)&eh2s[kb + 4 * hf + 8 * q];
      acc[4*q+0] = v.x; acc[4*q+1] = v.y; acc[4*q+2] = v.z; acc[4*q+3] = v.w;
    }
    const int baseo = c32 * 256 + hf * 16;
    const int swz = (c32 & 15) << 4;
#pragma unroll
    for (int ds = 0; ds < 8; ++ds) {
      const int o = (baseo + ds * 32) ^ swz;
      f16x8 ea = *(const f16x8*)(buf + o);
      acc = __builtin_amdgcn_mfma_f32_32x32x16_f16(ea, xh[ds], acc, 0, 0, 0);
      acc = __builtin_amdgcn_mfma_f32_32x32x16_f16(ea, xl[ds], acc, 0, 0, 0);
    }
    // packed top-3: low 10 mantissa bits <- (1023 - k); fmax/fmin sort network
    const int tb = 1023 - kb - 4 * hf;
#pragma unroll
    for (int r = 0; r < 16; ++r) {
      unsigned pc = (unsigned)(tb - ((r & 3) + 8 * (r >> 2)));
      float p = __uint_as_float((__float_as_uint(acc[r]) & 0xFFFFFC00u) | pc);
      float n1 = fmaxf(v1, p);
      float r1 = fminf(v1, p);
      float n2 = fmaxf(v2, r1);
      float r2 = fminf(v2, r1);
      v3 = fmaxf(v3, r2);
      v1 = n1; v2 = n2;
    }
    // ONE barrier: everyone done reading buf[c&1]; pg0's chunk-(c+1) glds
    // drained by syncthreads' vmcnt(0) -> buf[(c+1)&1] ready for next iter.
    __syncthreads();
    if (pg == 0 && c < 6) {   // prefetch chunk c+2 into the freed buffer
#pragma unroll
      for (int i = 0; i < 8; ++i) {
        int o = i * 1024 + lane * 16;
        int s = o ^ (((o >> 8) & 15) << 4);
        glds16(gq + (c + 2) * 8192 + s, sbuf + (c & 1) * 8192 + i * 1024);
      }
    }
  }

  // ---- merge hf halves (packed values preserve (score,k) order) ----
  {
    float b1 = __shfl_xor(v1, 32, 64);
    float b2 = __shfl_xor(v2, 32, 64);
    float b3 = __shfl_xor(v3, 32, 64);
    float c1 = fmaxf(v1, b1);
    float x1 = fminf(v1, b1);
    float m2 = fmaxf(v2, b2);
    float c2 = fmaxf(x1, m2);
    float c3 = fmaxf(fminf(x1, m2), fmaxf(v3, b3));
    if (hf == 0) {
      kcnd[(kq * 3 + 0) * 64 + pw] = 1023 - (int)(__float_as_uint(c1) & 1023u);
      kcnd[(kq * 3 + 1) * 64 + pw] = 1023 - (int)(__float_as_uint(c2) & 1023u);
      kcnd[(kq * 3 + 2) * 64 + pw] = 1023 - (int)(__float_as_uint(c3) & 1023u);
    }
  }
  __syncthreads();

  // ---- exact fp32 rescore of 12 candidates: sc = x.e - |e|^2/2 (maximize) ----
#pragma unroll
  for (int rep = 0; rep < 2; ++rep) {
    const int task = rep * 512 + tid;
    if (task < 768) {
      const int p = task & 63, cand = task >> 6;
      const int kc = kcnd[cand * 64 + p];
      const float* xc = x + bOff + t0 + p;
      const float* er = emb + (size_t)kc * 128;
      float dsum = 0.f;
#pragma unroll 4
      for (int d4 = 0; d4 < 128; d4 += 4) {
        float4 e4 = *(const float4*)&er[d4];
        dsum = fmaf(xc[(size_t)(d4 + 0) * 2048], e4.x, dsum);
        dsum = fmaf(xc[(size_t)(d4 + 1) * 2048], e4.y, dsum);
        dsum = fmaf(xc[(size_t)(d4 + 2) * 2048], e4.z, dsum);
        dsum = fmaf(xc[(size_t)(d4 + 3) * 2048], e4.w, dsum);
      }
      scs[cand * 64 + p] = dsum + eh2s[kc];
    }
  }
  __syncthreads();
  if (tid < 64) {
    float bs = scs[tid]; int bk = kcnd[tid];
#pragma unroll
    for (int cd = 1; cd < 12; ++cd) {
      float v = scs[cd * 64 + tid];
      int k = kcnd[cd * 64 + tid];
      if (v > bs || (v == bs && k < bk)) { bs = v; bk = k; }
    }
    kfin[tid] = bk;
  }
  __syncthreads();

  // ---- E1: gather emb rows -> qt (slot-XOR swizzled), overlays streams ----
  {
    float* qt = (float*)smem;
    const int p = tid >> 3, seg = tid & 7;
    const float* er = emb + (size_t)kfin[p] * 128 + seg * 16;
#pragma unroll
    for (int j = 0; j < 4; ++j) {
      int slot = seg * 4 + j;
      int sw = slot ^ (p & 31);
      *(float4*)(smem + p * 512 + sw * 16) = *(const float4*)&er[j * 4];
    }
  }
  __syncthreads();

  // ---- E2: lane = point; read qt along d, coalesced stores along t ----
  float lsum = 0.f;
  {
    const int p = tid & 63, jb = tid >> 6;
    const float* xg = x + bOff + t0 + p;
    float* og = out + bOff + t0 + p;
#pragma unroll
    for (int i = 0; i < 4; ++i) {
      int slot = jb * 4 + i;
      int sw = slot ^ (p & 31);
      float4 q4 = *(const float4*)(smem + p * 512 + sw * 16);
      float qa[4] = {q4.x, q4.y, q4.z, q4.w};
      int dd = slot * 4;
#pragma unroll
      for (int i2 = 0; i2 < 4; ++i2) {
        float xv = xg[(size_t)(dd + i2) * 2048];
        float df = qa[i2] - xv;
        lsum = fmaf(df, df, lsum);
        og[(size_t)(dd + i2) * 2048] = qa[i2];
      }
    }
  }
#pragma unroll
  for (int off = 32; off; off >>= 1) lsum += __shfl_down(lsum, off, 64);
  if (lane == 0) wsum[w] = lsum;
  __syncthreads();
  if (tid == 0) {
    float s = 0.f;
#pragma unroll
    for (int i = 0; i < 8; ++i) s += wsum[i];
    partial[blk] = s;
  }
}

__global__ void vq_loss(const float* __restrict__ partial, float* __restrict__ out) {
  int lane = threadIdx.x;  // 64 threads, 512 partials
  float s = 0.f;
#pragma unroll
  for (int i = 0; i < 8; ++i) s += partial[i * 64 + lane];
#pragma unroll
  for (int off = 32; off; off >>= 1) s += __shfl_down(s, off, 64);
  if (lane == 0) out[4194304] = 1.25f * s / 4194304.0f;
}

extern "C" void kernel_launch(void* const* d_in, const int* in_sizes, int n_in,
                              void* d_out, int out_size, void* d_ws, size_t ws_size,
                              hipStream_t stream) {
  const float* x   = (const float*)d_in[0];   // [16,1,128,2048]
  const float* emb = (const float*)d_in[1];   // [1024,128]
  float* out = (float*)d_out;
  char* ws = (char*)d_ws;
  _Float16* ehg = (_Float16*)ws;              // 256 KB
  float* eh2g = (float*)(ws + 262144);        // 4 KB
  float* partial = (float*)(ws + 266240);     // 2 KB (512 floats)
  vq_prep<<<64, 256, 0, stream>>>(emb, ehg, eh2g);
  vq_main<<<512, 512, 0, stream>>>(x, emb, ehg, eh2g, out, partial);
  vq_loss<<<1, 64, 0, stream>>>(partial, out);
}